// Round 3
// baseline (1012.361 us; speedup 1.0000x reference)
//
#include <hip/hip_runtime.h>
#include <stdint.h>

#define D_MODEL 2048
#define N_HEADS 16
#define HEAD_D  128
#define BATCH   2
#define SEQ     2048
#define MTOT    (BATCH*SEQ)   // 4096

typedef __bf16 bf16x8 __attribute__((ext_vector_type(8)));
typedef float  f32x4  __attribute__((ext_vector_type(4)));
typedef unsigned short u16x8 __attribute__((ext_vector_type(8)));
typedef unsigned short u16x4 __attribute__((ext_vector_type(4)));

#define MFMA16(a,b,c) __builtin_amdgcn_mfma_f32_16x16x32_bf16(a, b, c, 0, 0, 0)

__device__ __forceinline__ unsigned short f2bf(float f) {
  unsigned u = __builtin_bit_cast(unsigned, f);
  u += 0x7fffu + ((u >> 16) & 1u);
  return (unsigned short)(u >> 16);
}

__device__ __forceinline__ bf16x8 ld_frag(const unsigned short* p) {
  u16x8 raw = *(const u16x8*)p;
  return __builtin_bit_cast(bf16x8, raw);
}

__device__ __forceinline__ void gload16(const void* g, void* lds) {
  __builtin_amdgcn_global_load_lds(
      (const __attribute__((address_space(1))) unsigned int*)g,
      (__attribute__((address_space(3))) unsigned int*)lds, 16, 0, 0);
}

// ---------------- fp32 -> bf16 conversion (16B/lane) ----------------
__global__ __launch_bounds__(256) void f32_to_bf16_k(const float* __restrict__ in,
                                                     unsigned short* __restrict__ out,
                                                     int n8) {
  int i = blockIdx.x * 256 + threadIdx.x;
  if (i >= n8) return;
  const float4* p = (const float4*)in + (size_t)i * 2;
  float4 a = p[0], b = p[1];
  u16x8 o;
  o[0] = f2bf(a.x); o[1] = f2bf(a.y); o[2] = f2bf(a.z); o[3] = f2bf(a.w);
  o[4] = f2bf(b.x); o[5] = f2bf(b.y); o[6] = f2bf(b.z); o[7] = f2bf(b.w);
  *((u16x8*)out + i) = o;
}

// ---------------- GEMM: C = A(MxK) * B(NxK)^T, bf16 in, fp32 acc ----------------
// MODE 0: C0 fp32 row-major (MxN).
// MODE 1: fused QKV: gcol in [0,6144): which=gcol>>11 -> 0:Q (B,H,T,D) bf16 in C0,
//         1:K (B,H,T,D) bf16 in C1, 2:V^T (B,H,D,T) bf16 in C2.
template<int MODE>
__global__ __launch_bounds__(256) void gemm_bt(const unsigned short* __restrict__ A,
                                               const unsigned short* __restrict__ B,
                                               void* __restrict__ C0, void* __restrict__ C1,
                                               void* __restrict__ C2,
                                               int M, int N, int K) {
  __shared__ __align__(16) unsigned short As[128 * 32];
  __shared__ __align__(16) unsigned short Bs[128 * 32];
  const int tid  = threadIdx.x;
  const int lane = tid & 63;
  const int w    = tid >> 6;
  const int wr   = w >> 1, wc = w & 1;

  // bijective chunked XCD swizzle (nwg % 8 == 0 for all our grids)
  const int gx = gridDim.x;
  int bx = blockIdx.x, by = blockIdx.y;
  const int nwg = gx * gridDim.y;
  if ((nwg & 7) == 0) {
    const int lid = by * gx + bx;
    const int cpx = nwg >> 3;
    const int swz = (lid & 7) * cpx + (lid >> 3);
    bx = swz % gx; by = swz / gx;
  }
  const int brow = by * 128;
  const int bcol = bx * 128;

  const int e0 = (w * 2) * 512 + lane * 8;
  const int e1 = (w * 2 + 1) * 512 + lane * 8;
  const int r0 = e0 >> 5, cc0 = e0 & 31;
  const int r1 = e1 >> 5, cc1 = e1 & 31;
  const unsigned short* Ap0 = A + (size_t)(brow + r0) * K + cc0;
  const unsigned short* Ap1 = A + (size_t)(brow + r1) * K + cc1;
  const unsigned short* Bp0 = B + (size_t)(bcol + r0) * K + cc0;
  const unsigned short* Bp1 = B + (size_t)(bcol + r1) * K + cc1;
  unsigned short* As0 = &As[(w * 2) * 512];
  unsigned short* As1 = &As[(w * 2 + 1) * 512];
  unsigned short* Bs0 = &Bs[(w * 2) * 512];
  unsigned short* Bs1 = &Bs[(w * 2 + 1) * 512];

  f32x4 acc[4][4] = {};
  const int la = lane & 15;
  const int lb = (lane >> 4) * 8;

  for (int kt = 0; kt < K; kt += 32) {
    gload16(Ap0 + kt, As0);
    gload16(Ap1 + kt, As1);
    gload16(Bp0 + kt, Bs0);
    gload16(Bp1 + kt, Bs1);
    __syncthreads();
    bf16x8 af[4], bfr[4];
#pragma unroll
    for (int m = 0; m < 4; ++m)
      af[m] = ld_frag(&As[(wr * 64 + m * 16 + la) * 32 + lb]);
#pragma unroll
    for (int n = 0; n < 4; ++n)
      bfr[n] = ld_frag(&Bs[(wc * 64 + n * 16 + la) * 32 + lb]);
#pragma unroll
    for (int m = 0; m < 4; ++m)
#pragma unroll
      for (int n = 0; n < 4; ++n)
        acc[m][n] = MFMA16(af[m], bfr[n], acc[m][n]);
    __syncthreads();
  }

  const int rowb = (lane >> 4) * 4;
#pragma unroll
  for (int m = 0; m < 4; ++m) {
#pragma unroll
    for (int n = 0; n < 4; ++n) {
      const int gcol = bcol + wc * 64 + n * 16 + la;
      const int grow0 = brow + wr * 64 + m * 16 + rowb;
      if (MODE == 0) {
#pragma unroll
        for (int j = 0; j < 4; ++j)
          ((float*)C0)[(size_t)(grow0 + j) * N + gcol] = acc[m][n][j];
      } else {
        const int which = gcol >> 11;           // uniform per (block, wc, n)
        const int c2 = gcol & 2047;
        const int hh = c2 >> 7, dd = c2 & 127;
        const int bb = grow0 >> 11, tt = grow0 & (SEQ - 1);
        if (which == 2) {
          u16x4 pk;
#pragma unroll
          for (int j = 0; j < 4; ++j) pk[j] = f2bf(acc[m][n][j]);
          *(u16x4*)&((unsigned short*)C2)[(((size_t)bb * N_HEADS + hh) * HEAD_D + dd) * SEQ + tt] = pk;
        } else {
          unsigned short* dst = (which == 0) ? (unsigned short*)C0 : (unsigned short*)C1;
#pragma unroll
          for (int j = 0; j < 4; ++j)
            dst[(((size_t)bb * N_HEADS + hh) * SEQ + tt + j) * HEAD_D + dd] = f2bf(acc[m][n][j]);
        }
      }
    }
  }
}

// ---------------- causal ALiBi flash attention, paired q-tiles ----------------
// Straight-line softmax via macro on NAMED local arrays (no address-taking:
// round-2's lambda with f32x4* params demoted acc/m/l to scratch -> 2.7 GB HBM).
#define SOFTMAX_TILE(S, M, L, ACC, QG0, DIAG, KV0, PROW0)                          \
  do {                                                                             \
    float corr_[4];                                                                \
    float pe_[4][4];                                                               \
    _Pragma("unroll")                                                              \
    for (int j = 0; j < 4; ++j) {                                                  \
      const int qgj_ = (QG0) + j;                                                  \
      float mx_ = -1e30f;                                                          \
      _Pragma("unroll")                                                            \
      for (int c = 0; c < 4; ++c) {                                                \
        const int kvg_ = (KV0) + c * 16 + la;                                      \
        float sv_ = fmaf(S[c][j], scale, slope * (float)(kvg_ - qgj_));            \
        if ((DIAG) && (kvg_ > qgj_)) sv_ = -1e30f;                                 \
        pe_[c][j] = sv_;                                                           \
        mx_ = fmaxf(mx_, sv_);                                                     \
      }                                                                            \
      mx_ = fmaxf(mx_, __shfl_xor(mx_, 1));                                        \
      mx_ = fmaxf(mx_, __shfl_xor(mx_, 2));                                        \
      mx_ = fmaxf(mx_, __shfl_xor(mx_, 4));                                        \
      mx_ = fmaxf(mx_, __shfl_xor(mx_, 8));                                        \
      const float nm_ = fmaxf(M[j], mx_);                                          \
      const float cr_ = __expf(M[j] - nm_);                                        \
      corr_[j] = cr_;                                                              \
      float rs_ = 0.f;                                                             \
      _Pragma("unroll")                                                            \
      for (int c = 0; c < 4; ++c) {                                                \
        const float e_ = __expf(pe_[c][j] - nm_);                                  \
        pe_[c][j] = e_;                                                            \
        rs_ += e_;                                                                 \
      }                                                                            \
      rs_ += __shfl_xor(rs_, 1);                                                   \
      rs_ += __shfl_xor(rs_, 2);                                                   \
      rs_ += __shfl_xor(rs_, 4);                                                   \
      rs_ += __shfl_xor(rs_, 8);                                                   \
      L[j] = L[j] * cr_ + rs_;                                                     \
      M[j] = nm_;                                                                  \
    }                                                                              \
    _Pragma("unroll")                                                              \
    for (int n = 0; n < 8; ++n) {                                                  \
      _Pragma("unroll")                                                            \
      for (int j = 0; j < 4; ++j) ACC[n][j] *= corr_[j];                           \
    }                                                                              \
    _Pragma("unroll")                                                              \
    for (int c = 0; c < 4; ++c) {                                                  \
      _Pragma("unroll")                                                            \
      for (int j = 0; j < 4; ++j) {                                                \
        const int row_ = (PROW0) + lq * 4 + j;                                     \
        const int cb_ = (c * 16 + la) * 2;                                         \
        *(unsigned short*)((char*)Ps[w] + row_ * 128 + (cb_ ^ ((row_ & 7) << 4)))  \
            = f2bf(pe_[c][j]);                                                     \
      }                                                                            \
    }                                                                              \
  } while (0)

// Q,K: (BH,T,D) bf16.  VT: (BH,D,T) bf16.  O: (B,T,H*D) bf16.
// Block handles q-tiles {qp, 31-qp}: exactly 33 tile-units per block.
__global__ __launch_bounds__(256, 2) void attn_k(const unsigned short* __restrict__ Q,
                                                 const unsigned short* __restrict__ K,
                                                 const unsigned short* __restrict__ VT,
                                                 unsigned short* __restrict__ O) {
  __shared__ __align__(16) unsigned short Ks[2][64 * HEAD_D];   // 2x16 KB
  __shared__ __align__(16) unsigned short Vs[2][HEAD_D * 64];   // 2x16 KB
  __shared__ __align__(16) unsigned short Ps[4][32 * 64];       // 16 KB

  const int tid = threadIdx.x, lane = tid & 63, w = tid >> 6;
  // chunked XCD swizzle over 512 blocks: XCD gets 64 consecutive ids = 4 heads
  const int lid = blockIdx.x;
  const int swz = (lid & 7) * 64 + (lid >> 3);
  const int qp = swz & 15;
  const int h  = (swz >> 4) & 15;
  const int b  = swz >> 8;
  const int bh = b * N_HEADS + h;
  const int qtA = qp, qtB = 31 - qp;
  const int q0A = qtA * 64, q0B = qtB * 64;

  const float slope = exp2f(-0.5f * (float)(h + 1));
  const float scale = 0.08838834764831845f;   // 1/sqrt(128)
  const int la = lane & 15;
  const int lq = lane >> 4;

  const size_t kbase  = (size_t)bh * SEQ * HEAD_D;
  const size_t vtbase = (size_t)bh * HEAD_D * SEQ;

  bf16x8 qfA[4], qfB[4];
  {
    const size_t qa = ((size_t)bh * SEQ + q0A + w * 16 + la) * HEAD_D + lq * 8;
    const size_t qb = ((size_t)bh * SEQ + q0B + w * 16 + la) * HEAD_D + lq * 8;
#pragma unroll
    for (int kk = 0; kk < 4; ++kk) {
      qfA[kk] = ld_frag(&Q[qa + kk * 32]);
      qfB[kk] = ld_frag(&Q[qb + kk * 32]);
    }
  }

  f32x4 accA[8] = {}, accB[8] = {};
  float mA[4] = {-1e30f, -1e30f, -1e30f, -1e30f};
  float mB[4] = {-1e30f, -1e30f, -1e30f, -1e30f};
  float lA[4] = {0.f, 0.f, 0.f, 0.f};
  float lB[4] = {0.f, 0.f, 0.f, 0.f};

  auto stage = [&](int it, int bsel) {
    const int kv0 = it * 64;
#pragma unroll
    for (int s = 0; s < 4; ++s) {
      const int p = (w * 4 + s) * 1024 + lane * 16;
      const int row = p >> 8, cb = p & 255;
      const int col = (cb ^ ((row & 7) << 4)) >> 1;
      gload16(&K[kbase + (size_t)(kv0 + row) * HEAD_D + col], &Ks[bsel][(w * 4 + s) * 512]);
    }
#pragma unroll
    for (int s = 0; s < 4; ++s) {
      const int p = (w * 4 + s) * 1024 + lane * 16;
      const int d = p >> 7, cb = p & 127;
      const int col = (cb ^ ((d & 7) << 4)) >> 1;
      gload16(&VT[vtbase + (size_t)d * SEQ + kv0 + col], &Vs[bsel][(w * 4 + s) * 512]);
    }
  };

  stage(0, 0);   // prologue: 8 loads in flight

  for (int it = 0; it <= qtB; ++it) {
    const int cur = it & 1;
    const int kv0 = it * 64;
    const bool activeA = (it <= qtA);

    if (it < qtB) {
      stage(it + 1, cur ^ 1);                            // +8 -> 16 outstanding
      asm volatile("s_waitcnt vmcnt(8)" ::: "memory");   // current tile landed
    } else {
      asm volatile("s_waitcnt vmcnt(0)" ::: "memory");
    }
    __builtin_amdgcn_sched_barrier(0);
    __builtin_amdgcn_s_barrier();

    // ---- QK^T (K frags shared between both q-tiles) ----
    f32x4 sA[4] = {{0.f,0.f,0.f,0.f},{0.f,0.f,0.f,0.f},{0.f,0.f,0.f,0.f},{0.f,0.f,0.f,0.f}};
    f32x4 sB[4] = {{0.f,0.f,0.f,0.f},{0.f,0.f,0.f,0.f},{0.f,0.f,0.f,0.f},{0.f,0.f,0.f,0.f}};
    if (activeA) {
#pragma unroll
      for (int c = 0; c < 4; ++c) {
        const int row = c * 16 + la;
#pragma unroll
        for (int kk = 0; kk < 4; ++kk) {
          const int cb = kk * 64 + lq * 16;
          bf16x8 kf = ld_frag((const unsigned short*)((const char*)Ks[cur] + row * 256 + (cb ^ ((row & 7) << 4))));
          sA[c] = MFMA16(qfA[kk], kf, sA[c]);
          sB[c] = MFMA16(qfB[kk], kf, sB[c]);
        }
      }
    } else {
#pragma unroll
      for (int c = 0; c < 4; ++c) {
        const int row = c * 16 + la;
#pragma unroll
        for (int kk = 0; kk < 4; ++kk) {
          const int cb = kk * 64 + lq * 16;
          bf16x8 kf = ld_frag((const unsigned short*)((const char*)Ks[cur] + row * 256 + (cb ^ ((row & 7) << 4))));
          sB[c] = MFMA16(qfB[kk], kf, sB[c]);
        }
      }
    }

    // ---- softmax + P (macro: no address-taking, all constant indices) ----
    if (activeA)
      SOFTMAX_TILE(sA, mA, lA, accA, q0A + w * 16 + lq * 4, it == qtA, kv0, 0);
    SOFTMAX_TILE(sB, mB, lB, accB, q0B + w * 16 + lq * 4, it == qtB, kv0, 16);

    asm volatile("s_waitcnt lgkmcnt(0)" ::: "memory");   // P writes visible (wave-local)
    __builtin_amdgcn_sched_barrier(0);

    // ---- PV (V frags shared between both q-tiles) ----
#pragma unroll
    for (int kk = 0; kk < 2; ++kk) {
      const int pcb = kk * 64 + lq * 16;
      const int sw = (la & 7) << 4;
      bf16x8 pfB = ld_frag((const unsigned short*)((const char*)Ps[w] + (16 + la) * 128 + (pcb ^ sw)));
      bf16x8 pfA;
      if (activeA)
        pfA = ld_frag((const unsigned short*)((const char*)Ps[w] + la * 128 + (pcb ^ sw)));
#pragma unroll
      for (int n = 0; n < 8; ++n) {
        const int d = n * 16 + la;
        bf16x8 vf = ld_frag((const unsigned short*)((const char*)Vs[cur] + d * 128 + (pcb ^ ((d & 7) << 4))));
        accB[n] = MFMA16(pfB, vf, accB[n]);
        if (activeA) accA[n] = MFMA16(pfA, vf, accA[n]);
      }
    }

    __builtin_amdgcn_s_barrier();   // all waves done reading buf[cur] before restage
  }

  // ---- epilogue ----
#pragma unroll
  for (int j = 0; j < 4; ++j) {
    const float invA = 1.0f / lA[j];
    const float invB = 1.0f / lB[j];
    const int qA = q0A + w * 16 + lq * 4 + j;
    const int qB = q0B + w * 16 + lq * 4 + j;
    const size_t oA = ((size_t)b * SEQ + qA) * D_MODEL + (size_t)h * HEAD_D;
    const size_t oB = ((size_t)b * SEQ + qB) * D_MODEL + (size_t)h * HEAD_D;
#pragma unroll
    for (int n = 0; n < 8; ++n) {
      const int d = n * 16 + la;
      O[oA + d] = f2bf(accA[n][j] * invA);
      O[oB + d] = f2bf(accB[n][j] * invB);
    }
  }
}

// ---------------- launcher ----------------
extern "C" void kernel_launch(void* const* d_in, const int* in_sizes, int n_in,
                              void* d_out, int out_size, void* d_ws, size_t ws_size,
                              hipStream_t stream) {
  (void)in_sizes; (void)n_in; (void)out_size; (void)ws_size;
  const float* x  = (const float*)d_in[0];
  const float* Wq = (const float*)d_in[1];
  const float* Wk = (const float*)d_in[2];
  const float* Wv = (const float*)d_in[3];
  const float* Wo = (const float*)d_in[4];

  char* ws = (char*)d_ws;
  unsigned short* xb = (unsigned short*)(ws + 0);          // 16 MiB
  unsigned short* wq = (unsigned short*)(ws + 16777216);   // 8 MiB  (wq|wk|wv contiguous)
  unsigned short* wk = (unsigned short*)(ws + 25165824);   // 8 MiB
  unsigned short* wv = (unsigned short*)(ws + 33554432);   // 8 MiB
  unsigned short* wo = (unsigned short*)(ws + 41943040);   // 8 MiB
  unsigned short* q  = (unsigned short*)(ws + 50331648);   // 16 MiB
  unsigned short* k  = (unsigned short*)(ws + 67108864);   // 16 MiB
  unsigned short* vt = (unsigned short*)(ws + 83886080);   // 16 MiB
  unsigned short* o  = (unsigned short*)(ws + 0);          // aliases xb (dead after QKV GEMM)

  f32_to_bf16_k<<<4096, 256, 0, stream>>>(x,  xb, (MTOT * D_MODEL) / 8);
  f32_to_bf16_k<<<2048, 256, 0, stream>>>(Wq, wq, (D_MODEL * D_MODEL) / 8);
  f32_to_bf16_k<<<2048, 256, 0, stream>>>(Wk, wk, (D_MODEL * D_MODEL) / 8);
  f32_to_bf16_k<<<2048, 256, 0, stream>>>(Wv, wv, (D_MODEL * D_MODEL) / 8);
  f32_to_bf16_k<<<2048, 256, 0, stream>>>(Wo, wo, (D_MODEL * D_MODEL) / 8);

  // fused QKV projection: N = 6144, writes q, k, and V^T directly
  dim3 g1(3 * D_MODEL / 128, MTOT / 128);   // (48, 32)
  gemm_bt<1><<<g1, 256, 0, stream>>>(xb, wq, q, k, vt, MTOT, 3 * D_MODEL, D_MODEL);

  attn_k<<<512, 256, 0, stream>>>(q, k, vt, o);

  dim3 g2(D_MODEL / 128, MTOT / 128);       // (16, 32)
  gemm_bt<0><<<g2, 256, 0, stream>>>(o, wo, d_out, nullptr, nullptr, MTOT, D_MODEL, D_MODEL);
}

// Round 4
// 1011.939 us; speedup vs baseline: 1.0004x; 1.0004x over previous
//
#include <hip/hip_runtime.h>
#include <stdint.h>

#define D_MODEL 2048
#define N_HEADS 16
#define HEAD_D  128
#define BATCH   2
#define SEQ     2048
#define MTOT    (BATCH*SEQ)   // 4096

typedef __bf16 bf16x8 __attribute__((ext_vector_type(8)));
typedef float  f32x4  __attribute__((ext_vector_type(4)));
typedef unsigned short u16x8 __attribute__((ext_vector_type(8)));
typedef unsigned short u16x4 __attribute__((ext_vector_type(4)));

#define MFMA16(a,b,c) __builtin_amdgcn_mfma_f32_16x16x32_bf16(a, b, c, 0, 0, 0)

__device__ __forceinline__ unsigned short f2bf(float f) {
  unsigned u = __builtin_bit_cast(unsigned, f);
  u += 0x7fffu + ((u >> 16) & 1u);
  return (unsigned short)(u >> 16);
}

__device__ __forceinline__ bf16x8 ld_frag(const unsigned short* p) {
  u16x8 raw = *(const u16x8*)p;
  return __builtin_bit_cast(bf16x8, raw);
}

__device__ __forceinline__ void gload16(const void* g, void* lds) {
  __builtin_amdgcn_global_load_lds(
      (const __attribute__((address_space(1))) unsigned int*)g,
      (__attribute__((address_space(3))) unsigned int*)lds, 16, 0, 0);
}

// ---------------- fp32 -> bf16 conversion (16B/lane) ----------------
__global__ __launch_bounds__(256) void f32_to_bf16_k(const float* __restrict__ in,
                                                     unsigned short* __restrict__ out,
                                                     int n8) {
  int i = blockIdx.x * 256 + threadIdx.x;
  if (i >= n8) return;
  const float4* p = (const float4*)in + (size_t)i * 2;
  float4 a = p[0], b = p[1];
  u16x8 o;
  o[0] = f2bf(a.x); o[1] = f2bf(a.y); o[2] = f2bf(a.z); o[3] = f2bf(a.w);
  o[4] = f2bf(b.x); o[5] = f2bf(b.y); o[6] = f2bf(b.z); o[7] = f2bf(b.w);
  *((u16x8*)out + i) = o;
}

// ---------------- GEMM: C = A(MxK) * B(NxK)^T, bf16 in, fp32 acc ----------------
// MODE 0: C0 fp32 row-major (MxN).
// MODE 1: fused QKV: gcol in [0,6144): which=gcol>>11 -> 0:Q (B,H,T,D) bf16 in C0,
//         1:K (B,H,T,D) bf16 in C1, 2:V^T (B,H,D,T) bf16 in C2.
template<int MODE>
__global__ __launch_bounds__(256) void gemm_bt(const unsigned short* __restrict__ A,
                                               const unsigned short* __restrict__ B,
                                               void* __restrict__ C0, void* __restrict__ C1,
                                               void* __restrict__ C2,
                                               int M, int N, int K) {
  __shared__ __align__(16) unsigned short As[128 * 32];
  __shared__ __align__(16) unsigned short Bs[128 * 32];
  const int tid  = threadIdx.x;
  const int lane = tid & 63;
  const int w    = tid >> 6;
  const int wr   = w >> 1, wc = w & 1;

  // bijective chunked XCD swizzle (nwg % 8 == 0 for all our grids)
  const int gx = gridDim.x;
  int bx = blockIdx.x, by = blockIdx.y;
  const int nwg = gx * gridDim.y;
  if ((nwg & 7) == 0) {
    const int lid = by * gx + bx;
    const int cpx = nwg >> 3;
    const int swz = (lid & 7) * cpx + (lid >> 3);
    bx = swz % gx; by = swz / gx;
  }
  const int brow = by * 128;
  const int bcol = bx * 128;

  const int e0 = (w * 2) * 512 + lane * 8;
  const int e1 = (w * 2 + 1) * 512 + lane * 8;
  const int r0 = e0 >> 5, cc0 = e0 & 31;
  const int r1 = e1 >> 5, cc1 = e1 & 31;
  const unsigned short* Ap0 = A + (size_t)(brow + r0) * K + cc0;
  const unsigned short* Ap1 = A + (size_t)(brow + r1) * K + cc1;
  const unsigned short* Bp0 = B + (size_t)(bcol + r0) * K + cc0;
  const unsigned short* Bp1 = B + (size_t)(bcol + r1) * K + cc1;
  unsigned short* As0 = &As[(w * 2) * 512];
  unsigned short* As1 = &As[(w * 2 + 1) * 512];
  unsigned short* Bs0 = &Bs[(w * 2) * 512];
  unsigned short* Bs1 = &Bs[(w * 2 + 1) * 512];

  f32x4 acc[4][4] = {};
  const int la = lane & 15;
  const int lb = (lane >> 4) * 8;

  for (int kt = 0; kt < K; kt += 32) {
    gload16(Ap0 + kt, As0);
    gload16(Ap1 + kt, As1);
    gload16(Bp0 + kt, Bs0);
    gload16(Bp1 + kt, Bs1);
    __syncthreads();
    bf16x8 af[4], bfr[4];
#pragma unroll
    for (int m = 0; m < 4; ++m)
      af[m] = ld_frag(&As[(wr * 64 + m * 16 + la) * 32 + lb]);
#pragma unroll
    for (int n = 0; n < 4; ++n)
      bfr[n] = ld_frag(&Bs[(wc * 64 + n * 16 + la) * 32 + lb]);
#pragma unroll
    for (int m = 0; m < 4; ++m)
#pragma unroll
      for (int n = 0; n < 4; ++n)
        acc[m][n] = MFMA16(af[m], bfr[n], acc[m][n]);
    __syncthreads();
  }

  const int rowb = (lane >> 4) * 4;
#pragma unroll
  for (int m = 0; m < 4; ++m) {
#pragma unroll
    for (int n = 0; n < 4; ++n) {
      const int gcol = bcol + wc * 64 + n * 16 + la;
      const int grow0 = brow + wr * 64 + m * 16 + rowb;
      if (MODE == 0) {
#pragma unroll
        for (int j = 0; j < 4; ++j)
          ((float*)C0)[(size_t)(grow0 + j) * N + gcol] = acc[m][n][j];
      } else {
        const int which = gcol >> 11;           // uniform per (block, wc, n)
        const int c2 = gcol & 2047;
        const int hh = c2 >> 7, dd = c2 & 127;
        const int bb = grow0 >> 11, tt = grow0 & (SEQ - 1);
        if (which == 2) {
          u16x4 pk;
#pragma unroll
          for (int j = 0; j < 4; ++j) pk[j] = f2bf(acc[m][n][j]);
          *(u16x4*)&((unsigned short*)C2)[(((size_t)bb * N_HEADS + hh) * HEAD_D + dd) * SEQ + tt] = pk;
        } else {
          unsigned short* dst = (which == 0) ? (unsigned short*)C0 : (unsigned short*)C1;
#pragma unroll
          for (int j = 0; j < 4; ++j)
            dst[(((size_t)bb * N_HEADS + hh) * SEQ + tt + j) * HEAD_D + dd] = f2bf(acc[m][n][j]);
        }
      }
    }
  }
}

// ---------------- causal ALiBi flash attention, paired q-tiles ----------------
// ALL straight-line macros: NO lambdas anywhere (round-2/3 lesson: the stage
// lambda forced acc arrays to scratch -> 1.5 GB spill traffic per dispatch).

// stage K tile [64 rows][256 B] + VT tile [128 rows][128 B] into buffer BSEL,
// XOR-swizzled content via pre-swizzled global source, linear LDS dest.
#define STAGE_KV(IT, BSEL)                                                          \
  do {                                                                              \
    const int kv0_ = (IT) * 64;                                                     \
    _Pragma("unroll")                                                               \
    for (int s = 0; s < 4; ++s) {                                                   \
      const int p_ = (w * 4 + s) * 1024 + lane * 16;                                \
      const int row_ = p_ >> 8, cb_ = p_ & 255;                                     \
      const int col_ = (cb_ ^ ((row_ & 7) << 4)) >> 1;                              \
      gload16(&K[kbase + (size_t)(kv0_ + row_) * HEAD_D + col_],                    \
              &Ks[BSEL][(w * 4 + s) * 512]);                                        \
    }                                                                               \
    _Pragma("unroll")                                                               \
    for (int s = 0; s < 4; ++s) {                                                   \
      const int p_ = (w * 4 + s) * 1024 + lane * 16;                                \
      const int d_ = p_ >> 7, cb_ = p_ & 127;                                       \
      const int col_ = (cb_ ^ ((d_ & 7) << 4)) >> 1;                                \
      gload16(&VT[vtbase + (size_t)d_ * SEQ + kv0_ + col_],                         \
              &Vs[BSEL][(w * 4 + s) * 512]);                                        \
    }                                                                               \
  } while (0)

#define SOFTMAX_TILE(S, M, L, ACC, QG0, DIAG, KV0, PROW0)                          \
  do {                                                                             \
    float corr_[4];                                                                \
    float pe_[4][4];                                                               \
    _Pragma("unroll")                                                              \
    for (int j = 0; j < 4; ++j) {                                                  \
      const int qgj_ = (QG0) + j;                                                  \
      float mx_ = -1e30f;                                                          \
      _Pragma("unroll")                                                            \
      for (int c = 0; c < 4; ++c) {                                                \
        const int kvg_ = (KV0) + c * 16 + la;                                      \
        float sv_ = fmaf(S[c][j], scale, slope * (float)(kvg_ - qgj_));            \
        if ((DIAG) && (kvg_ > qgj_)) sv_ = -1e30f;                                 \
        pe_[c][j] = sv_;                                                           \
        mx_ = fmaxf(mx_, sv_);                                                     \
      }                                                                            \
      mx_ = fmaxf(mx_, __shfl_xor(mx_, 1));                                        \
      mx_ = fmaxf(mx_, __shfl_xor(mx_, 2));                                        \
      mx_ = fmaxf(mx_, __shfl_xor(mx_, 4));                                        \
      mx_ = fmaxf(mx_, __shfl_xor(mx_, 8));                                        \
      const float nm_ = fmaxf(M[j], mx_);                                          \
      const float cr_ = __expf(M[j] - nm_);                                        \
      corr_[j] = cr_;                                                              \
      float rs_ = 0.f;                                                             \
      _Pragma("unroll")                                                            \
      for (int c = 0; c < 4; ++c) {                                                \
        const float e_ = __expf(pe_[c][j] - nm_);                                  \
        pe_[c][j] = e_;                                                            \
        rs_ += e_;                                                                 \
      }                                                                            \
      rs_ += __shfl_xor(rs_, 1);                                                   \
      rs_ += __shfl_xor(rs_, 2);                                                   \
      rs_ += __shfl_xor(rs_, 4);                                                   \
      rs_ += __shfl_xor(rs_, 8);                                                   \
      L[j] = L[j] * cr_ + rs_;                                                     \
      M[j] = nm_;                                                                  \
    }                                                                              \
    _Pragma("unroll")                                                              \
    for (int n = 0; n < 8; ++n) {                                                  \
      _Pragma("unroll")                                                            \
      for (int j = 0; j < 4; ++j) ACC[n][j] *= corr_[j];                           \
    }                                                                              \
    _Pragma("unroll")                                                              \
    for (int c = 0; c < 4; ++c) {                                                  \
      _Pragma("unroll")                                                            \
      for (int j = 0; j < 4; ++j) {                                                \
        const int row_ = (PROW0) + lq * 4 + j;                                     \
        const int cb_ = (c * 16 + la) * 2;                                         \
        *(unsigned short*)((char*)Ps[w] + row_ * 128 + (cb_ ^ ((row_ & 7) << 4)))  \
            = f2bf(pe_[c][j]);                                                     \
      }                                                                            \
    }                                                                              \
  } while (0)

// Q,K: (BH,T,D) bf16.  VT: (BH,D,T) bf16.  O: (B,T,H*D) bf16.
// Block handles q-tiles {qp, 31-qp}: exactly 33 tile-units per block.
// LDS 80 KB caps at 2 blocks/CU = 2 waves/EU; clamp the allocator to exactly
// that so it gets the full 256-VGPR budget (r2/r3: open-ended bound -> 128+spill).
__global__ __launch_bounds__(256)
__attribute__((amdgpu_waves_per_eu(2, 2)))
void attn_k(const unsigned short* __restrict__ Q,
            const unsigned short* __restrict__ K,
            const unsigned short* __restrict__ VT,
            unsigned short* __restrict__ O) {
  __shared__ __align__(16) unsigned short Ks[2][64 * HEAD_D];   // 2x16 KB
  __shared__ __align__(16) unsigned short Vs[2][HEAD_D * 64];   // 2x16 KB
  __shared__ __align__(16) unsigned short Ps[4][32 * 64];       // 16 KB

  const int tid = threadIdx.x, lane = tid & 63, w = tid >> 6;
  // chunked XCD swizzle over 512 blocks: XCD gets 64 consecutive ids = 4 heads
  const int lid = blockIdx.x;
  const int swz = (lid & 7) * 64 + (lid >> 3);
  const int qp = swz & 15;
  const int h  = (swz >> 4) & 15;
  const int b  = swz >> 8;
  const int bh = b * N_HEADS + h;
  const int qtA = qp, qtB = 31 - qp;
  const int q0A = qtA * 64, q0B = qtB * 64;

  const float slope = exp2f(-0.5f * (float)(h + 1));
  const float scale = 0.08838834764831845f;   // 1/sqrt(128)
  const int la = lane & 15;
  const int lq = lane >> 4;

  const size_t kbase  = (size_t)bh * SEQ * HEAD_D;
  const size_t vtbase = (size_t)bh * HEAD_D * SEQ;

  bf16x8 qfA[4], qfB[4];
  {
    const size_t qa = ((size_t)bh * SEQ + q0A + w * 16 + la) * HEAD_D + lq * 8;
    const size_t qb = ((size_t)bh * SEQ + q0B + w * 16 + la) * HEAD_D + lq * 8;
#pragma unroll
    for (int kk = 0; kk < 4; ++kk) {
      qfA[kk] = ld_frag(&Q[qa + kk * 32]);
      qfB[kk] = ld_frag(&Q[qb + kk * 32]);
    }
  }

  f32x4 accA[8] = {}, accB[8] = {};
  float mA[4] = {-1e30f, -1e30f, -1e30f, -1e30f};
  float mB[4] = {-1e30f, -1e30f, -1e30f, -1e30f};
  float lA[4] = {0.f, 0.f, 0.f, 0.f};
  float lB[4] = {0.f, 0.f, 0.f, 0.f};

  STAGE_KV(0, 0);   // prologue: 8 loads in flight

  for (int it = 0; it <= qtB; ++it) {
    const int cur = it & 1;
    const int kv0 = it * 64;
    const bool activeA = (it <= qtA);

    if (it < qtB) {
      STAGE_KV(it + 1, cur ^ 1);                         // +8 -> 16 outstanding
      asm volatile("s_waitcnt vmcnt(8)" ::: "memory");   // current tile landed
    } else {
      asm volatile("s_waitcnt vmcnt(0)" ::: "memory");
    }
    __builtin_amdgcn_sched_barrier(0);
    __builtin_amdgcn_s_barrier();

    // ---- QK^T (K frags shared between both q-tiles) ----
    f32x4 sA[4] = {{0.f,0.f,0.f,0.f},{0.f,0.f,0.f,0.f},{0.f,0.f,0.f,0.f},{0.f,0.f,0.f,0.f}};
    f32x4 sB[4] = {{0.f,0.f,0.f,0.f},{0.f,0.f,0.f,0.f},{0.f,0.f,0.f,0.f},{0.f,0.f,0.f,0.f}};
    if (activeA) {
#pragma unroll
      for (int c = 0; c < 4; ++c) {
        const int row = c * 16 + la;
#pragma unroll
        for (int kk = 0; kk < 4; ++kk) {
          const int cb = kk * 64 + lq * 16;
          bf16x8 kf = ld_frag((const unsigned short*)((const char*)Ks[cur] + row * 256 + (cb ^ ((row & 7) << 4))));
          sA[c] = MFMA16(qfA[kk], kf, sA[c]);
          sB[c] = MFMA16(qfB[kk], kf, sB[c]);
        }
      }
    } else {
#pragma unroll
      for (int c = 0; c < 4; ++c) {
        const int row = c * 16 + la;
#pragma unroll
        for (int kk = 0; kk < 4; ++kk) {
          const int cb = kk * 64 + lq * 16;
          bf16x8 kf = ld_frag((const unsigned short*)((const char*)Ks[cur] + row * 256 + (cb ^ ((row & 7) << 4))));
          sB[c] = MFMA16(qfB[kk], kf, sB[c]);
        }
      }
    }

    // ---- softmax + P (straight-line, constant indices) ----
    if (activeA)
      SOFTMAX_TILE(sA, mA, lA, accA, q0A + w * 16 + lq * 4, it == qtA, kv0, 0);
    SOFTMAX_TILE(sB, mB, lB, accB, q0B + w * 16 + lq * 4, it == qtB, kv0, 16);

    asm volatile("s_waitcnt lgkmcnt(0)" ::: "memory");   // P writes visible (wave-local)
    __builtin_amdgcn_sched_barrier(0);

    // ---- PV (V frags shared between both q-tiles) ----
#pragma unroll
    for (int kk = 0; kk < 2; ++kk) {
      const int pcb = kk * 64 + lq * 16;
      const int sw = (la & 7) << 4;
      bf16x8 pfB = ld_frag((const unsigned short*)((const char*)Ps[w] + (16 + la) * 128 + (pcb ^ sw)));
      bf16x8 pfA;
      if (activeA)
        pfA = ld_frag((const unsigned short*)((const char*)Ps[w] + la * 128 + (pcb ^ sw)));
#pragma unroll
      for (int n = 0; n < 8; ++n) {
        const int d = n * 16 + la;
        bf16x8 vf = ld_frag((const unsigned short*)((const char*)Vs[cur] + d * 128 + (pcb ^ ((d & 7) << 4))));
        accB[n] = MFMA16(pfB, vf, accB[n]);
        if (activeA) accA[n] = MFMA16(pfA, vf, accA[n]);
      }
    }

    __builtin_amdgcn_s_barrier();   // all waves done reading buf[cur] before restage
  }

  // ---- epilogue ----
#pragma unroll
  for (int j = 0; j < 4; ++j) {
    const float invA = 1.0f / lA[j];
    const float invB = 1.0f / lB[j];
    const int qA = q0A + w * 16 + lq * 4 + j;
    const int qB = q0B + w * 16 + lq * 4 + j;
    const size_t oA = ((size_t)b * SEQ + qA) * D_MODEL + (size_t)h * HEAD_D;
    const size_t oB = ((size_t)b * SEQ + qB) * D_MODEL + (size_t)h * HEAD_D;
#pragma unroll
    for (int n = 0; n < 8; ++n) {
      const int d = n * 16 + la;
      O[oA + d] = f2bf(accA[n][j] * invA);
      O[oB + d] = f2bf(accB[n][j] * invB);
    }
  }
}

// ---------------- launcher ----------------
extern "C" void kernel_launch(void* const* d_in, const int* in_sizes, int n_in,
                              void* d_out, int out_size, void* d_ws, size_t ws_size,
                              hipStream_t stream) {
  (void)in_sizes; (void)n_in; (void)out_size; (void)ws_size;
  const float* x  = (const float*)d_in[0];
  const float* Wq = (const float*)d_in[1];
  const float* Wk = (const float*)d_in[2];
  const float* Wv = (const float*)d_in[3];
  const float* Wo = (const float*)d_in[4];

  char* ws = (char*)d_ws;
  unsigned short* xb = (unsigned short*)(ws + 0);          // 16 MiB
  unsigned short* wq = (unsigned short*)(ws + 16777216);   // 8 MiB  (wq|wk|wv contiguous)
  unsigned short* wk = (unsigned short*)(ws + 25165824);   // 8 MiB
  unsigned short* wv = (unsigned short*)(ws + 33554432);   // 8 MiB
  unsigned short* wo = (unsigned short*)(ws + 41943040);   // 8 MiB
  unsigned short* q  = (unsigned short*)(ws + 50331648);   // 16 MiB
  unsigned short* k  = (unsigned short*)(ws + 67108864);   // 16 MiB
  unsigned short* vt = (unsigned short*)(ws + 83886080);   // 16 MiB
  unsigned short* o  = (unsigned short*)(ws + 0);          // aliases xb (dead after QKV GEMM)

  f32_to_bf16_k<<<4096, 256, 0, stream>>>(x,  xb, (MTOT * D_MODEL) / 8);
  f32_to_bf16_k<<<2048, 256, 0, stream>>>(Wq, wq, (D_MODEL * D_MODEL) / 8);
  f32_to_bf16_k<<<2048, 256, 0, stream>>>(Wk, wk, (D_MODEL * D_MODEL) / 8);
  f32_to_bf16_k<<<2048, 256, 0, stream>>>(Wv, wv, (D_MODEL * D_MODEL) / 8);
  f32_to_bf16_k<<<2048, 256, 0, stream>>>(Wo, wo, (D_MODEL * D_MODEL) / 8);

  // fused QKV projection: N = 6144, writes q, k, and V^T directly
  dim3 g1(3 * D_MODEL / 128, MTOT / 128);   // (48, 32)
  gemm_bt<1><<<g1, 256, 0, stream>>>(xb, wq, q, k, vt, MTOT, 3 * D_MODEL, D_MODEL);

  attn_k<<<512, 256, 0, stream>>>(q, k, vt, o);

  dim3 g2(D_MODEL / 128, MTOT / 128);       // (16, 32)
  gemm_bt<0><<<g2, 256, 0, stream>>>(o, wo, d_out, nullptr, nullptr, MTOT, D_MODEL, D_MODEL);
}

// Round 5
// 320.925 us; speedup vs baseline: 3.1545x; 3.1532x over previous
//
#include <hip/hip_runtime.h>
#include <stdint.h>

#define D_MODEL 2048
#define N_HEADS 16
#define HEAD_D  128
#define BATCH   2
#define SEQ     2048
#define MTOT    (BATCH*SEQ)   // 4096

typedef __bf16 bf16x8 __attribute__((ext_vector_type(8)));
typedef float  f32x4  __attribute__((ext_vector_type(4)));
typedef unsigned short u16x8 __attribute__((ext_vector_type(8)));
typedef unsigned short u16x4 __attribute__((ext_vector_type(4)));

#define MFMA16(a,b,c) __builtin_amdgcn_mfma_f32_16x16x32_bf16(a, b, c, 0, 0, 0)

__device__ __forceinline__ unsigned short f2bf(float f) {
  unsigned u = __builtin_bit_cast(unsigned, f);
  u += 0x7fffu + ((u >> 16) & 1u);
  return (unsigned short)(u >> 16);
}

__device__ __forceinline__ bf16x8 ld_frag(const unsigned short* p) {
  u16x8 raw = *(const u16x8*)p;
  return __builtin_bit_cast(bf16x8, raw);
}

__device__ __forceinline__ void gload16(const void* g, void* lds) {
  __builtin_amdgcn_global_load_lds(
      (const __attribute__((address_space(1))) unsigned int*)g,
      (__attribute__((address_space(3))) unsigned int*)lds, 16, 0, 0);
}

// ---------------- fp32 -> bf16 conversion (16B/lane) ----------------
__global__ __launch_bounds__(256) void f32_to_bf16_k(const float* __restrict__ in,
                                                     unsigned short* __restrict__ out,
                                                     int n8) {
  int i = blockIdx.x * 256 + threadIdx.x;
  if (i >= n8) return;
  const float4* p = (const float4*)in + (size_t)i * 2;
  float4 a = p[0], b = p[1];
  u16x8 o;
  o[0] = f2bf(a.x); o[1] = f2bf(a.y); o[2] = f2bf(a.z); o[3] = f2bf(a.w);
  o[4] = f2bf(b.x); o[5] = f2bf(b.y); o[6] = f2bf(b.z); o[7] = f2bf(b.w);
  *((u16x8*)out + i) = o;
}

// ---------------- GEMM: C = A(MxK) * B(NxK)^T, bf16 in, fp32 acc ----------------
// MODE 0: C0 fp32 row-major (MxN).
// MODE 1: fused QKV: gcol in [0,6144): which=gcol>>11 -> 0:Q (B,H,T,D) bf16 in C0,
//         1:K (B,H,T,D) bf16 in C1, 2:V^T (B,H,D,T) bf16 in C2.
template<int MODE>
__global__ __launch_bounds__(256) void gemm_bt(const unsigned short* __restrict__ A,
                                               const unsigned short* __restrict__ B,
                                               void* __restrict__ C0, void* __restrict__ C1,
                                               void* __restrict__ C2,
                                               int M, int N, int K) {
  __shared__ __align__(16) unsigned short As[128 * 32];
  __shared__ __align__(16) unsigned short Bs[128 * 32];
  const int tid  = threadIdx.x;
  const int lane = tid & 63;
  const int w    = tid >> 6;
  const int wr   = w >> 1, wc = w & 1;

  // bijective chunked XCD swizzle (nwg % 8 == 0 for all our grids)
  const int gx = gridDim.x;
  int bx = blockIdx.x, by = blockIdx.y;
  const int nwg = gx * gridDim.y;
  if ((nwg & 7) == 0) {
    const int lid = by * gx + bx;
    const int cpx = nwg >> 3;
    const int swz = (lid & 7) * cpx + (lid >> 3);
    bx = swz % gx; by = swz / gx;
  }
  const int brow = by * 128;
  const int bcol = bx * 128;

  const int e0 = (w * 2) * 512 + lane * 8;
  const int e1 = (w * 2 + 1) * 512 + lane * 8;
  const int r0 = e0 >> 5, cc0 = e0 & 31;
  const int r1 = e1 >> 5, cc1 = e1 & 31;
  const unsigned short* Ap0 = A + (size_t)(brow + r0) * K + cc0;
  const unsigned short* Ap1 = A + (size_t)(brow + r1) * K + cc1;
  const unsigned short* Bp0 = B + (size_t)(bcol + r0) * K + cc0;
  const unsigned short* Bp1 = B + (size_t)(bcol + r1) * K + cc1;
  unsigned short* As0 = &As[(w * 2) * 512];
  unsigned short* As1 = &As[(w * 2 + 1) * 512];
  unsigned short* Bs0 = &Bs[(w * 2) * 512];
  unsigned short* Bs1 = &Bs[(w * 2 + 1) * 512];

  f32x4 acc[4][4] = {};
  const int la = lane & 15;
  const int lb = (lane >> 4) * 8;

  for (int kt = 0; kt < K; kt += 32) {
    gload16(Ap0 + kt, As0);
    gload16(Ap1 + kt, As1);
    gload16(Bp0 + kt, Bs0);
    gload16(Bp1 + kt, Bs1);
    __syncthreads();
    bf16x8 af[4], bfr[4];
#pragma unroll
    for (int m = 0; m < 4; ++m)
      af[m] = ld_frag(&As[(wr * 64 + m * 16 + la) * 32 + lb]);
#pragma unroll
    for (int n = 0; n < 4; ++n)
      bfr[n] = ld_frag(&Bs[(wc * 64 + n * 16 + la) * 32 + lb]);
#pragma unroll
    for (int m = 0; m < 4; ++m)
#pragma unroll
      for (int n = 0; n < 4; ++n)
        acc[m][n] = MFMA16(af[m], bfr[n], acc[m][n]);
    __syncthreads();
  }

  const int rowb = (lane >> 4) * 4;
#pragma unroll
  for (int m = 0; m < 4; ++m) {
#pragma unroll
    for (int n = 0; n < 4; ++n) {
      const int gcol = bcol + wc * 64 + n * 16 + la;
      const int grow0 = brow + wr * 64 + m * 16 + rowb;
      if (MODE == 0) {
#pragma unroll
        for (int j = 0; j < 4; ++j)
          ((float*)C0)[(size_t)(grow0 + j) * N + gcol] = acc[m][n][j];
      } else {
        const int which = gcol >> 11;           // uniform per (block, wc, n)
        const int c2 = gcol & 2047;
        const int hh = c2 >> 7, dd = c2 & 127;
        const int bb = grow0 >> 11, tt = grow0 & (SEQ - 1);
        if (which == 2) {
          u16x4 pk;
#pragma unroll
          for (int j = 0; j < 4; ++j) pk[j] = f2bf(acc[m][n][j]);
          *(u16x4*)&((unsigned short*)C2)[(((size_t)bb * N_HEADS + hh) * HEAD_D + dd) * SEQ + tt] = pk;
        } else {
          unsigned short* dst = (which == 0) ? (unsigned short*)C0 : (unsigned short*)C1;
#pragma unroll
          for (int j = 0; j < 4; ++j)
            dst[(((size_t)bb * N_HEADS + hh) * SEQ + tt + j) * HEAD_D + dd] = f2bf(acc[m][n][j]);
        }
      }
    }
  }
}

// ---------------- causal ALiBi flash attention ----------------
// SINGLE q-tile of state per thread (r1's proven ~104-VGPR codegen; the r2-r4
// paired design carried ~190 live VGPRs -> allocator stuck at 128 -> 1.5 GB
// scratch traffic). Balance comes from SEQUENTIAL pairing: block processes
// q-tile qp fully, then q-tile 31-qp, as a flat list of exactly 33 (tile,kv)
// units. Double-buffered K/V staging with counted vmcnt(8).

#define STAGE_KV(U, BSEL)                                                           \
  do {                                                                              \
    const int kv0_ = (((U) <= qtA) ? (U) : (U) - qtA - 1) * 64;                     \
    _Pragma("unroll")                                                               \
    for (int s = 0; s < 4; ++s) {                                                   \
      const int p_ = (w * 4 + s) * 1024 + lane * 16;                                \
      const int row_ = p_ >> 8, cb_ = p_ & 255;                                     \
      const int col_ = (cb_ ^ ((row_ & 7) << 4)) >> 1;                              \
      gload16(&K[kbase + (size_t)(kv0_ + row_) * HEAD_D + col_],                    \
              &Ks[BSEL][(w * 4 + s) * 512]);                                        \
    }                                                                               \
    _Pragma("unroll")                                                               \
    for (int s = 0; s < 4; ++s) {                                                   \
      const int p_ = (w * 4 + s) * 1024 + lane * 16;                                \
      const int d_ = p_ >> 7, cb_ = p_ & 127;                                       \
      const int col_ = (cb_ ^ ((d_ & 7) << 4)) >> 1;                                \
      gload16(&VT[vtbase + (size_t)d_ * SEQ + kv0_ + col_],                         \
              &Vs[BSEL][(w * 4 + s) * 512]);                                        \
    }                                                                               \
  } while (0)

#define LOAD_Q(Q0)                                                                  \
  do {                                                                              \
    const size_t qa_ = ((size_t)bh * SEQ + (Q0) + w * 16 + la) * HEAD_D + lq * 8;   \
    _Pragma("unroll")                                                               \
    for (int kk = 0; kk < 4; ++kk) qf[kk] = ld_frag(&Q[qa_ + kk * 32]);             \
  } while (0)

#define EPILOGUE(Q0)                                                                \
  do {                                                                              \
    _Pragma("unroll")                                                               \
    for (int j = 0; j < 4; ++j) {                                                   \
      const float inv_ = 1.0f / lrow[j];                                            \
      const int q_ = (Q0) + w * 16 + lq * 4 + j;                                    \
      const size_t ob_ = ((size_t)b * SEQ + q_) * D_MODEL + (size_t)h * HEAD_D;     \
      _Pragma("unroll")                                                             \
      for (int n = 0; n < 8; ++n) O[ob_ + n * 16 + la] = f2bf(acc[n][j] * inv_);    \
    }                                                                               \
  } while (0)

#define SOFTMAX_TILE(S, QG0, DIAG, KV0)                                            \
  do {                                                                             \
    float corr_[4];                                                                \
    float pe_[4][4];                                                               \
    _Pragma("unroll")                                                              \
    for (int j = 0; j < 4; ++j) {                                                  \
      const int qgj_ = (QG0) + j;                                                  \
      float mx_ = -1e30f;                                                          \
      _Pragma("unroll")                                                            \
      for (int c = 0; c < 4; ++c) {                                                \
        const int kvg_ = (KV0) + c * 16 + la;                                      \
        float sv_ = fmaf(S[c][j], scale, slope * (float)(kvg_ - qgj_));            \
        if ((DIAG) && (kvg_ > qgj_)) sv_ = -1e30f;                                 \
        pe_[c][j] = sv_;                                                           \
        mx_ = fmaxf(mx_, sv_);                                                     \
      }                                                                            \
      mx_ = fmaxf(mx_, __shfl_xor(mx_, 1));                                        \
      mx_ = fmaxf(mx_, __shfl_xor(mx_, 2));                                        \
      mx_ = fmaxf(mx_, __shfl_xor(mx_, 4));                                        \
      mx_ = fmaxf(mx_, __shfl_xor(mx_, 8));                                        \
      const float nm_ = fmaxf(mrow[j], mx_);                                       \
      const float cr_ = __expf(mrow[j] - nm_);                                     \
      corr_[j] = cr_;                                                              \
      float rs_ = 0.f;                                                             \
      _Pragma("unroll")                                                            \
      for (int c = 0; c < 4; ++c) {                                                \
        const float e_ = __expf(pe_[c][j] - nm_);                                  \
        pe_[c][j] = e_;                                                            \
        rs_ += e_;                                                                 \
      }                                                                            \
      rs_ += __shfl_xor(rs_, 1);                                                   \
      rs_ += __shfl_xor(rs_, 2);                                                   \
      rs_ += __shfl_xor(rs_, 4);                                                   \
      rs_ += __shfl_xor(rs_, 8);                                                   \
      lrow[j] = lrow[j] * cr_ + rs_;                                               \
      mrow[j] = nm_;                                                               \
    }                                                                              \
    _Pragma("unroll")                                                              \
    for (int n = 0; n < 8; ++n) {                                                  \
      _Pragma("unroll")                                                            \
      for (int j = 0; j < 4; ++j) acc[n][j] *= corr_[j];                           \
    }                                                                              \
    _Pragma("unroll")                                                              \
    for (int c = 0; c < 4; ++c) {                                                  \
      _Pragma("unroll")                                                            \
      for (int j = 0; j < 4; ++j) {                                                \
        const int row_ = lq * 4 + j;                                               \
        const int cb_ = (c * 16 + la) * 2;                                         \
        *(unsigned short*)((char*)Ps[w] + row_ * 128 + (cb_ ^ ((row_ & 7) << 4)))  \
            = f2bf(pe_[c][j]);                                                     \
      }                                                                            \
    }                                                                              \
  } while (0)

// Q,K: (BH,T,D) bf16.  VT: (BH,D,T) bf16.  O: (B,T,H*D) bf16.
__global__ __launch_bounds__(256)
void attn_k(const unsigned short* __restrict__ Q,
            const unsigned short* __restrict__ K,
            const unsigned short* __restrict__ VT,
            unsigned short* __restrict__ O) {
  __shared__ __align__(16) unsigned short Ks[2][64 * HEAD_D];   // 2x16 KB
  __shared__ __align__(16) unsigned short Vs[2][HEAD_D * 64];   // 2x16 KB
  __shared__ __align__(16) unsigned short Ps[4][16 * 64];       // 8 KB  (72 KB total)

  const int tid = threadIdx.x, lane = tid & 63, w = tid >> 6;
  // chunked XCD swizzle over 512 blocks: XCD gets 64 consecutive ids = 4 heads
  const int lid = blockIdx.x;
  const int swz = (lid & 7) * 64 + (lid >> 3);
  const int qp = swz & 15;
  const int h  = (swz >> 4) & 15;
  const int b  = swz >> 8;
  const int bh = b * N_HEADS + h;
  const int qtA = qp, qtB = 31 - qp;
  const int q0A = qtA * 64, q0B = qtB * 64;

  const float slope = exp2f(-0.5f * (float)(h + 1));
  const float scale = 0.08838834764831845f;   // 1/sqrt(128)
  const int la = lane & 15;
  const int lq = lane >> 4;

  const size_t kbase  = (size_t)bh * SEQ * HEAD_D;
  const size_t vtbase = (size_t)bh * HEAD_D * SEQ;

  bf16x8 qf[4];
  f32x4 acc[8] = {};
  float mrow[4] = {-1e30f, -1e30f, -1e30f, -1e30f};
  float lrow[4] = {0.f, 0.f, 0.f, 0.f};
  int q0cur = q0A;

  LOAD_Q(q0A);
  STAGE_KV(0, 0);   // prologue: unit 0's 8 loads in flight

  for (int u = 0; u < 33; ++u) {
    if (u < 32) {
      STAGE_KV(u + 1, (u + 1) & 1);                    // +8 -> 16 outstanding
      asm volatile("s_waitcnt vmcnt(8)" ::: "memory");  // unit-u tile landed
    } else {
      asm volatile("s_waitcnt vmcnt(0)" ::: "memory");
    }
    __builtin_amdgcn_sched_barrier(0);
    __builtin_amdgcn_s_barrier();

    // tile switch A -> B (uniform branch, once per block)
    if (u == qtA + 1) {
      EPILOGUE(q0A);
      LOAD_Q(q0B);
      q0cur = q0B;
#pragma unroll
      for (int n = 0; n < 8; ++n)
#pragma unroll
        for (int j = 0; j < 4; ++j) acc[n][j] = 0.f;
#pragma unroll
      for (int j = 0; j < 4; ++j) { mrow[j] = -1e30f; lrow[j] = 0.f; }
    }

    const int cur = u & 1;
    const int kv0 = ((u <= qtA) ? u : u - qtA - 1) * 64;
    const bool diag = (u == qtA) || (u == 32);

    // ---- QK^T (16x64 per wave) ----
    f32x4 s4[4] = {{0.f,0.f,0.f,0.f},{0.f,0.f,0.f,0.f},{0.f,0.f,0.f,0.f},{0.f,0.f,0.f,0.f}};
#pragma unroll
    for (int c = 0; c < 4; ++c) {
      const int row = c * 16 + la;
#pragma unroll
      for (int kk = 0; kk < 4; ++kk) {
        const int cb = kk * 64 + lq * 16;
        bf16x8 kf = ld_frag((const unsigned short*)((const char*)Ks[cur] + row * 256 + (cb ^ ((row & 7) << 4))));
        s4[c] = MFMA16(qf[kk], kf, s4[c]);
      }
    }

    // ---- softmax + P-store (straight-line, constant indices) ----
    SOFTMAX_TILE(s4, q0cur + w * 16 + lq * 4, diag, kv0);

    asm volatile("s_waitcnt lgkmcnt(0)" ::: "memory");   // P ds_writes done (wave-local)
    __builtin_amdgcn_sched_barrier(0);

    // ---- PV ----
#pragma unroll
    for (int kk = 0; kk < 2; ++kk) {
      const int pcb = kk * 64 + lq * 16;
      const int paddr = la * 128 + (pcb ^ ((la & 7) << 4));
      bf16x8 pf = ld_frag((const unsigned short*)((const char*)Ps[w] + paddr));
#pragma unroll
      for (int n = 0; n < 8; ++n) {
        const int d = n * 16 + la;
        bf16x8 vf = ld_frag((const unsigned short*)((const char*)Vs[cur] + d * 128 + (pcb ^ ((d & 7) << 4))));
        acc[n] = MFMA16(pf, vf, acc[n]);
      }
    }

    __builtin_amdgcn_s_barrier();   // all waves done reading buf[cur] before restage
  }

  EPILOGUE(q0B);
}

// ---------------- launcher ----------------
extern "C" void kernel_launch(void* const* d_in, const int* in_sizes, int n_in,
                              void* d_out, int out_size, void* d_ws, size_t ws_size,
                              hipStream_t stream) {
  (void)in_sizes; (void)n_in; (void)out_size; (void)ws_size;
  const float* x  = (const float*)d_in[0];
  const float* Wq = (const float*)d_in[1];
  const float* Wk = (const float*)d_in[2];
  const float* Wv = (const float*)d_in[3];
  const float* Wo = (const float*)d_in[4];

  char* ws = (char*)d_ws;
  unsigned short* xb = (unsigned short*)(ws + 0);          // 16 MiB
  unsigned short* wq = (unsigned short*)(ws + 16777216);   // 8 MiB  (wq|wk|wv contiguous)
  unsigned short* wk = (unsigned short*)(ws + 25165824);   // 8 MiB
  unsigned short* wv = (unsigned short*)(ws + 33554432);   // 8 MiB
  unsigned short* wo = (unsigned short*)(ws + 41943040);   // 8 MiB
  unsigned short* q  = (unsigned short*)(ws + 50331648);   // 16 MiB
  unsigned short* k  = (unsigned short*)(ws + 67108864);   // 16 MiB
  unsigned short* vt = (unsigned short*)(ws + 83886080);   // 16 MiB
  unsigned short* o  = (unsigned short*)(ws + 0);          // aliases xb (dead after QKV GEMM)

  f32_to_bf16_k<<<4096, 256, 0, stream>>>(x,  xb, (MTOT * D_MODEL) / 8);
  f32_to_bf16_k<<<2048, 256, 0, stream>>>(Wq, wq, (D_MODEL * D_MODEL) / 8);
  f32_to_bf16_k<<<2048, 256, 0, stream>>>(Wk, wk, (D_MODEL * D_MODEL) / 8);
  f32_to_bf16_k<<<2048, 256, 0, stream>>>(Wv, wv, (D_MODEL * D_MODEL) / 8);
  f32_to_bf16_k<<<2048, 256, 0, stream>>>(Wo, wo, (D_MODEL * D_MODEL) / 8);

  // fused QKV projection: N = 6144, writes q, k, and V^T directly
  dim3 g1(3 * D_MODEL / 128, MTOT / 128);   // (48, 32)
  gemm_bt<1><<<g1, 256, 0, stream>>>(xb, wq, q, k, vt, MTOT, 3 * D_MODEL, D_MODEL);

  attn_k<<<512, 256, 0, stream>>>(q, k, vt, o);

  dim3 g2(D_MODEL / 128, MTOT / 128);       // (16, 32)
  gemm_bt<0><<<g2, 256, 0, stream>>>(o, wo, d_out, nullptr, nullptr, MTOT, D_MODEL, D_MODEL);
}